// Round 6
// baseline (118.126 us; speedup 1.0000x reference)
//
#include <hip/hip_runtime.h>
#include <hip/hip_bf16.h>
#if !__has_builtin(__builtin_amdgcn_cvt_pk_fp8_f32)
#include <hip/hip_fp8.h>
#endif

typedef unsigned char u8;
typedef long long i64;
typedef i64 i64x2 __attribute__((ext_vector_type(2)));
typedef float f32x4 __attribute__((ext_vector_type(4)));

#define NROW 8192
#define NHALF 4096
#define DIM 256
#define TILES 64                       // 8192 / 128
#define NBLK (TILES * (TILES + 1) / 2) // 2080 upper-triangular tiles
#define PBLK 512                       // k_prep blocks (one 16-row strip each)

// gbuf layout (floats): [0..255]=colsum  [256]=ss  [257]=c4  [288+s*16]=32 acc slots
#define G_SS 256
#define G_C4 257
#define G_ACC 288
#define G_ZBYTES ((G_ACC + 32 * 16) * 4)

static __device__ __forceinline__ float fast_exp2(float x) {
#if __has_builtin(__builtin_amdgcn_exp2f)
  return __builtin_amdgcn_exp2f(x);
#else
  return exp2f(x);
#endif
}

// pack 4 floats -> 4 OCP e4m3 bytes (RNE, saturating) [k ascending in bytes]
static __device__ __forceinline__ unsigned pack4_fp8(float4 v) {
#if __has_builtin(__builtin_amdgcn_cvt_pk_fp8_f32)
  int p = 0;
  p = __builtin_amdgcn_cvt_pk_fp8_f32(v.x, v.y, p, false); // bytes 0,1
  p = __builtin_amdgcn_cvt_pk_fp8_f32(v.z, v.w, p, true);  // bytes 2,3
  return (unsigned)p;
#else
  __hip_fp8_e4m3 a(v.x), b(v.y), c(v.z), d(v.w);
  return (unsigned)a.__x | ((unsigned)b.__x << 8) | ((unsigned)c.__x << 16) |
         ((unsigned)d.__x << 24);
#endif
}

// Fragment-pair-major fp8 layout: element (row r, col k):
//   strip s=r>>4, pair p=k>>6, half h=(k>>5)&1, quad q=(k&31)>>3, j=k&7
//   byte index = ((s*4+p)*64 + q*16 + (r&15))*16 + h*8 + j
// => strip s occupies bytes [s*4096, (s+1)*4096): a 128-row tile (8 strips) is
// one LINEAR 32 KB region, and one wave dwordx4 at (pair fp, lane L) yields TWO
// MFMA A/B fragments: lane holds row 16*strip+(L&15), k=(L>>4)*8.. (A-layout).

// ---------------- K1: fp32->fp8 swizzled store + row |x|^2 + atomic partials
__global__ void k_prep(const float* __restrict__ src, const float* __restrict__ tgt,
                       u8* __restrict__ Xq, float* __restrict__ sq,
                       float* __restrict__ gbuf) {
  __shared__ float cps[4][DIM];
  int w = threadIdx.x >> 6, lane = threadIdx.x & 63;
  int s = blockIdx.x;
  int r0 = s * 16 + w * 4;
  // this lane covers k in [4*lane, 4*lane+4)
  int p = lane >> 4, h = (lane >> 3) & 1, q = (lane >> 1) & 3, j = 4 * (lane & 1);
  float4 ca = make_float4(0.f, 0.f, 0.f, 0.f);
  float ssw = 0.f;
#pragma unroll
  for (int rr = 0; rr < 4; ++rr) {
    int row = r0 + rr;
    const float* pp = (row < NHALF) ? (src + (size_t)row * DIM)
                                    : (tgt + (size_t)(row - NHALF) * DIM);
    float4 v = *(const float4*)(pp + lane * 4);
    size_t di = ((size_t)(s * 4 + p) * 64 + q * 16 + (row & 15)) * 16 + h * 8 + j;
    *(unsigned*)(Xq + di) = pack4_fp8(v);
    ca.x += v.x; ca.y += v.y; ca.z += v.z; ca.w += v.w;
    float sum = v.x * v.x + v.y * v.y + v.z * v.z + v.w * v.w;
#pragma unroll
    for (int off = 32; off > 0; off >>= 1) sum += __shfl_down(sum, off);
    if (lane == 0) { sq[row] = sum; ssw += sum; }
  }
  if (lane == 0) atomicAdd(gbuf + G_SS, ssw); // 4 atomics/block
  cps[w][lane * 4 + 0] = ca.x;
  cps[w][lane * 4 + 1] = ca.y;
  cps[w][lane * 4 + 2] = ca.z;
  cps[w][lane * 4 + 3] = ca.w;
  __syncthreads();
  int cc = threadIdx.x;
  atomicAdd(gbuf + cc, cps[0][cc] + cps[1][cc] + cps[2][cc] + cps[3][cc]);
}

// ---------------- K2: bandwidth scalar ---------------------------------------
__global__ void k_scal(float* __restrict__ gbuf) {
  int c = threadIdx.x, lane = c & 63, w = c >> 6;
  float vs = gbuf[c];
  float vn = vs * vs;
#pragma unroll
  for (int off = 32; off > 0; off >>= 1) vn += __shfl_down(vn, off);
  __shared__ float rv[4];
  if (lane == 0) rv[w] = vn;
  __syncthreads();
  if (c == 0) {
    double S  = (double)gbuf[G_SS];
    double VN = (double)rv[0] + rv[1] + rv[2] + rv[3];
    double suml2 = 2.0 * (double)NROW * S - 2.0 * VN;
    double bw = suml2 / ((double)NROW * NROW - NROW) / 4.0; // / KERNEL_MUL^(5/2)
    gbuf[G_C4] = (float)(1.4426950408889634 / (bw * 16.0)); // t = exp2(-l2*c4)
  }
}

// ---------------- K3: fused fp8 X*X^T + multi-RBF epilogue + signed reduce --
// 2080 blocks (upper-tri 128x128 tiles) x 256 threads (4 waves, 2x2 of 64x64).
// Whole K=256 tiles staged in LDS ONCE (linear 32 KB memcpy each, non-permuted
// global_load_lds width=16), single __syncthreads, then a barrier-free run of
// 32 ds_read_b128 + 128 MFMAs per wave. LDS 64 KB -> 2 blocks/CU.
__global__ __launch_bounds__(256, 2) void k_main(const u8* __restrict__ Xq,
                                                 const float* __restrict__ sq,
                                                 const float* __restrict__ gbuf,
                                                 float* __restrict__ accbuf) {
  __shared__ __align__(16) u8 Asm[32768];
  __shared__ __align__(16) u8 Bsm[32768];
  __shared__ float red[4];

  // linear triangle index -> (bi, bj), bj >= bi
  int bi = 0, rem = blockIdx.x;
  while (rem >= TILES - bi) { rem -= TILES - bi; ++bi; }
  int bj = bi + rem;

  int tid = threadIdx.x;
  int w = tid >> 6, lane = tid & 63;
  int wi = w >> 1, wj = w & 1;

  // ---- stage both 32 KB tiles (linear, coalesced, direct-to-LDS) ----
  const u8* Ag = Xq + (size_t)bi * 32768;
  const u8* Bg = Xq + (size_t)bj * 32768;
#pragma unroll
  for (int t = 0; t < 8; ++t) {
    int seg = t * 4 + w; // 32 segments of 1 KB each
    __builtin_amdgcn_global_load_lds(
        (const __attribute__((address_space(1))) void*)(Ag + seg * 1024 + lane * 16),
        (__attribute__((address_space(3))) void*)(Asm + seg * 1024), 16, 0, 0);
    __builtin_amdgcn_global_load_lds(
        (const __attribute__((address_space(1))) void*)(Bg + seg * 1024 + lane * 16),
        (__attribute__((address_space(3))) void*)(Bsm + seg * 1024), 16, 0, 0);
  }
  __syncthreads(); // drains vmcnt: staged tiles visible; ONLY barrier pre-epilogue

  f32x4 acc[4][4];
#pragma unroll
  for (int a = 0; a < 4; ++a)
#pragma unroll
    for (int b = 0; b < 4; ++b) acc[a][b] = (f32x4){0.f, 0.f, 0.f, 0.f};

  const i64x2* Al = (const i64x2*)Asm; // pair fp within tile: Al[fp*64 + lane]
  const i64x2* Bl = (const i64x2*)Bsm;

#pragma unroll
  for (int p = 0; p < 4; ++p) {
    i64x2 aP[4], bP[4];
#pragma unroll
    for (int mi = 0; mi < 4; ++mi)
      aP[mi] = Al[((wi * 4 + mi) * 4 + p) * 64 + lane];
#pragma unroll
    for (int ni = 0; ni < 4; ++ni)
      bP[ni] = Bl[((wj * 4 + ni) * 4 + p) * 64 + lane];
#pragma unroll
    for (int mi = 0; mi < 4; ++mi)
#pragma unroll
      for (int ni = 0; ni < 4; ++ni)
        acc[mi][ni] = __builtin_amdgcn_mfma_f32_16x16x32_fp8_fp8(
            aP[mi].x, bP[ni].x, acc[mi][ni], 0, 0, 0);
#pragma unroll
    for (int mi = 0; mi < 4; ++mi)
#pragma unroll
      for (int ni = 0; ni < 4; ++ni)
        acc[mi][ni] = __builtin_amdgcn_mfma_f32_16x16x32_fp8_fp8(
            aP[mi].y, bP[ni].y, acc[mi][ni], 0, 0, 0);
  }

  // Epilogue: l2 -> t + t^2 + t^4 + t^8 + t^16, signed sum.
  // C/D layout: col = lane&15, row = (lane>>4)*4 + reg (dtype-independent).
  float c4 = gbuf[G_C4];
  float wgt = ((bi < 32) == (bj < 32)) ? 1.f : -1.f; // quadrant sign s_i*s_j
  if (bi != bj) wgt *= 2.f;                          // symmetry: count (j,i) too
  bool diag = (bi == bj);
  int ib = bi * 128 + wi * 64 + (lane >> 4) * 4;
  int jb = bj * 128 + wj * 64 + (lane & 15);
  f32x4 sqi[4];
#pragma unroll
  for (int mi = 0; mi < 4; ++mi) sqi[mi] = *(const f32x4*)(sq + ib + mi * 16);
  float lsum = 0.f;
#pragma unroll
  for (int ni = 0; ni < 4; ++ni) {
    float sqj = sq[jb + ni * 16];
#pragma unroll
    for (int mi = 0; mi < 4; ++mi) {
#pragma unroll
      for (int r = 0; r < 4; ++r) {
        float l2 = sqi[mi][r] + sqj - 2.f * acc[mi][ni][r];
        float t  = fast_exp2(-l2 * c4);
        float t2 = t * t, t4 = t2 * t2, t8 = t4 * t4, t16 = t8 * t8;
        float tt = t + t2 + t4 + t8 + t16;
        // exact diagonal: K_ii = 5 (kills fp8 quantization bias on l2_ii)
        if (diag && (ib + mi * 16 + r) == (jb + ni * 16)) tt = 5.f;
        lsum += tt;
      }
    }
  }
#pragma unroll
  for (int off = 32; off > 0; off >>= 1) lsum += __shfl_down(lsum, off);
  if (lane == 0) red[w] = lsum;
  __syncthreads();
  if (tid == 0)
    atomicAdd(accbuf + (blockIdx.x & 31) * 16,
              wgt * (red[0] + red[1] + red[2] + red[3]));
}

// ---------------- K4: finalize ----------------------------------------------
__global__ void k_fin(const float* __restrict__ accbuf, float* __restrict__ out) {
  int lane = threadIdx.x & 63;
  float s = (lane < 32) ? accbuf[lane * 16] : 0.f;
#pragma unroll
  for (int off = 32; off > 0; off >>= 1) s += __shfl_down(s, off);
  if (threadIdx.x == 0) out[0] = s / 16777216.f; // / 4096^2
}

extern "C" void kernel_launch(void* const* d_in, const int* in_sizes, int n_in,
                              void* d_out, int out_size, void* d_ws, size_t ws_size,
                              hipStream_t stream) {
  const float* src = (const float*)d_in[0];
  const float* tgt = (const float*)d_in[1];
  char* ws = (char*)d_ws;
  u8* Xq = (u8*)ws;                                  // 2 MiB swizzled fp8
  size_t off = (size_t)NROW * DIM;
  float* sq = (float*)(ws + off);   off += NROW * 4; // 32 KiB row |x|^2
  float* gbuf = (float*)(ws + off);                  // colsum/ss/c4/acc slots
  float* out = (float*)d_out;

  hipMemsetAsync(gbuf, 0, G_ZBYTES, stream);
  k_prep<<<PBLK, 256, 0, stream>>>(src, tgt, Xq, sq, gbuf);
  k_scal<<<1, 256, 0, stream>>>(gbuf);
  k_main<<<NBLK, 256, 0, stream>>>(Xq, sq, gbuf, gbuf + G_ACC);
  k_fin<<<1, 64, 0, stream>>>(gbuf + G_ACC, out);
}

// Round 7
// 112.998 us; speedup vs baseline: 1.0454x; 1.0454x over previous
//
#include <hip/hip_runtime.h>
#include <hip/hip_bf16.h>
#if !__has_builtin(__builtin_amdgcn_cvt_pk_fp8_f32)
#include <hip/hip_fp8.h>
#endif

typedef unsigned char u8;
typedef int i32x4 __attribute__((ext_vector_type(4)));
typedef int i32x8 __attribute__((ext_vector_type(8)));
typedef float f32x4 __attribute__((ext_vector_type(4)));
typedef float f32x16 __attribute__((ext_vector_type(16)));

#define NROW 8192
#define NHALF 4096
#define DIM 256
#define TILES 64                       // 8192 / 128
#define NBLK (TILES * (TILES + 1) / 2) // 2080 upper-triangular tiles
#define PBLK 512                       // k_prep blocks (one 16-row strip each)

// gbuf layout (floats): [0..255]=colsum  [256]=ss  [288+s*16]=32 acc slots
#define G_SS 256
#define G_ACC 288
#define G_ZBYTES ((G_ACC + 32 * 16) * 4)

static __device__ __forceinline__ float fast_exp2(float x) {
#if __has_builtin(__builtin_amdgcn_exp2f)
  return __builtin_amdgcn_exp2f(x);
#else
  return exp2f(x);
#endif
}

// pack 4 floats -> 4 OCP e4m3 bytes (RNE, saturating) [k ascending in bytes]
static __device__ __forceinline__ unsigned pack4_fp8(float4 v) {
#if __has_builtin(__builtin_amdgcn_cvt_pk_fp8_f32)
  int p = 0;
  p = __builtin_amdgcn_cvt_pk_fp8_f32(v.x, v.y, p, false); // bytes 0,1
  p = __builtin_amdgcn_cvt_pk_fp8_f32(v.z, v.w, p, true);  // bytes 2,3
  return (unsigned)p;
#else
  __hip_fp8_e4m3 a(v.x), b(v.y), c(v.z), d(v.w);
  return (unsigned)a.__x | ((unsigned)b.__x << 8) | ((unsigned)c.__x << 16) |
         ((unsigned)d.__x << 24);
#endif
}

// 32x32x64-fragment-major fp8 layout. MFMA A/B operand (32x32x64 f8f6f4):
// lane l holds row m = l&31, k = (l>>5)*32 + byte(0..31) (8 VGPRs).
// Element (row r, col k): S = r>>5 (32-row strip), t = k>>6 (k-step),
//   khi = (k>>5)&1, half = (k>>4)&1, b = k&15
//   byte index = (((S*4 + t)*2 + half)*64 + khi*32 + (r&31))*16 + b
// => each fragment half is a contiguous 1 KB region; one wave dwordx4 at
//    lane*16 is perfectly coalesced; two such loads = one 8-VGPR fragment.

// ---------------- K1: fp32->fp8 swizzled store + row |x|^2 + atomic partials
__global__ void k_prep(const float* __restrict__ src, const float* __restrict__ tgt,
                       u8* __restrict__ Xq, float* __restrict__ sq,
                       float* __restrict__ gbuf) {
  __shared__ float cps[4][DIM];
  int w = threadIdx.x >> 6, lane = threadIdx.x & 63;
  int r0 = blockIdx.x * 16 + w * 4;
  // this lane covers k in [4*lane, 4*lane+4)
  int t = lane >> 4, khi = (lane >> 3) & 1, half = (lane >> 2) & 1;
  int b4 = (lane & 3) * 4;
  float4 ca = make_float4(0.f, 0.f, 0.f, 0.f);
  float ssw = 0.f;
#pragma unroll
  for (int rr = 0; rr < 4; ++rr) {
    int row = r0 + rr;
    const float* pp = (row < NHALF) ? (src + (size_t)row * DIM)
                                    : (tgt + (size_t)(row - NHALF) * DIM);
    float4 v = *(const float4*)(pp + lane * 4);
    int S = row >> 5, m5 = row & 31;
    size_t di = ((size_t)((S * 4 + t) * 2 + half) * 64 + khi * 32 + m5) * 16 + b4;
    *(unsigned*)(Xq + di) = pack4_fp8(v);
    ca.x += v.x; ca.y += v.y; ca.z += v.z; ca.w += v.w;
    float sum = v.x * v.x + v.y * v.y + v.z * v.z + v.w * v.w;
#pragma unroll
    for (int off = 32; off > 0; off >>= 1) sum += __shfl_down(sum, off);
    if (lane == 0) { sq[row] = sum; ssw += sum; }
  }
  if (lane == 0) atomicAdd(gbuf + G_SS, ssw); // 4 atomics/block
  cps[w][lane * 4 + 0] = ca.x;
  cps[w][lane * 4 + 1] = ca.y;
  cps[w][lane * 4 + 2] = ca.z;
  cps[w][lane * 4 + 3] = ca.w;
  __syncthreads();
  int cc = threadIdx.x;
  atomicAdd(gbuf + cc, cps[0][cc] + cps[1][cc] + cps[2][cc] + cps[3][cc]);
}

// ---------------- K2: fused fp8 X*X^T (MX 32x32x64) + RBF + signed reduce ---
// 2080 blocks (upper-tri 128x128 tiles) x 256 threads (4 waves, 2x2 of 64x64;
// each wave = 2x2 of 32x32 MFMA tiles). No LDS staging, no K-loop barriers;
// direct contiguous fragment loads from the L2-resident 2 MB matrix.
// Bandwidth scalar computed per-block from colsum partials (no k_scal pass).
__global__ __launch_bounds__(256, 4) void k_main(const u8* __restrict__ Xq,
                                                 const float* __restrict__ sq,
                                                 const float* __restrict__ gbuf,
                                                 float* __restrict__ accbuf) {
  __shared__ float red[4];
  __shared__ float c4sh;

  int tid = threadIdx.x;
  int w = tid >> 6, lane = tid & 63;

  // ---- per-block bandwidth scalar: c4 = log2(e)/(16*bw) ----
  {
    float v = gbuf[tid]; // colsum_c
    float vn = v * v;
#pragma unroll
    for (int off = 32; off > 0; off >>= 1) vn += __shfl_down(vn, off);
    if (lane == 0) red[w] = vn;
    __syncthreads();
    if (tid == 0) {
      double VN = (double)red[0] + red[1] + red[2] + red[3];
      double S  = (double)gbuf[G_SS];
      double suml2 = 2.0 * (double)NROW * S - 2.0 * VN;
      double bw = suml2 / ((double)NROW * NROW - NROW) / 4.0; // / 2^(5/2 floor)
      c4sh = (float)(1.4426950408889634 / (bw * 16.0));
    }
    __syncthreads();
  }

  // linear triangle index -> (bi, bj), bj >= bi
  int bi = 0, rem = blockIdx.x;
  while (rem >= TILES - bi) { rem -= TILES - bi; ++bi; }
  int bj = bi + rem;

  int wi = w >> 1, wj = w & 1;

  f32x16 acc[2][2];
#pragma unroll
  for (int a = 0; a < 2; ++a)
#pragma unroll
    for (int b = 0; b < 2; ++b) acc[a][b] = (f32x16)(0.f);

  const i32x4* X4 = (const i32x4*)Xq;
  const int Sa0 = bi * 4 + wi * 2; // this wave's two A 32-row strips
  const int Sb0 = bj * 4 + wj * 2; // this wave's two B 32-row strips

#pragma unroll 1
  for (int t = 0; t < 4; ++t) {
    i32x8 af[2], bf[2];
#pragma unroll
    for (int ti = 0; ti < 2; ++ti) {
      size_t R = (size_t)((Sa0 + ti) * 4 + t) * 2;
      i32x4 lo = X4[R * 64 + lane];
      i32x4 hi = X4[(R + 1) * 64 + lane];
      af[ti] = (i32x8){lo.x, lo.y, lo.z, lo.w, hi.x, hi.y, hi.z, hi.w};
    }
#pragma unroll
    for (int tj = 0; tj < 2; ++tj) {
      size_t R = (size_t)((Sb0 + tj) * 4 + t) * 2;
      i32x4 lo = X4[R * 64 + lane];
      i32x4 hi = X4[(R + 1) * 64 + lane];
      bf[tj] = (i32x8){lo.x, lo.y, lo.z, lo.w, hi.x, hi.y, hi.z, hi.w};
    }
#pragma unroll
    for (int ti = 0; ti < 2; ++ti)
#pragma unroll
      for (int tj = 0; tj < 2; ++tj)
        acc[ti][tj] = __builtin_amdgcn_mfma_scale_f32_32x32x64_f8f6f4(
            af[ti], bf[tj], acc[ti][tj], 0, 0, /*A,B fmt = fp8*/
            0, 0x7F,  /* scale A: opsel 0, E8M0 127 = 1.0 */
            0, 0x7F); /* scale B */
  }

  // Epilogue: l2 -> t + t^2 + t^4 + t^8 + t^16, signed sum.
  // 32x32 C/D layout: col = lane&31, row = (reg&3) + 8*(reg>>2) + 4*(lane>>5)
  float c4 = c4sh;
  float wgt = ((bi < 32) == (bj < 32)) ? 1.f : -1.f; // quadrant sign s_i*s_j
  if (bi != bj) wgt *= 2.f;                          // symmetry: count (j,i) too
  bool diag = (bi == bj);
  int q5 = lane >> 5, c5 = lane & 31;
  f32x4 sqi[2][4];
#pragma unroll
  for (int ti = 0; ti < 2; ++ti)
#pragma unroll
    for (int g = 0; g < 4; ++g)
      sqi[ti][g] = *(const f32x4*)(sq + bi * 128 + wi * 64 + ti * 32 + q5 * 4 + g * 8);
  float sqjv[2];
#pragma unroll
  for (int tj = 0; tj < 2; ++tj)
    sqjv[tj] = sq[bj * 128 + wj * 64 + tj * 32 + c5];

  float lsum = 0.f;
#pragma unroll
  for (int ti = 0; ti < 2; ++ti) {
#pragma unroll
    for (int tj = 0; tj < 2; ++tj) {
#pragma unroll
      for (int g = 0; g < 4; ++g) {
#pragma unroll
        for (int rr = 0; rr < 4; ++rr) {
          float l2 = sqi[ti][g][rr] + sqjv[tj] - 2.f * acc[ti][tj][g * 4 + rr];
          float t  = fast_exp2(-l2 * c4);
          float t2 = t * t, t4 = t2 * t2, t8 = t4 * t4, t16 = t8 * t8;
          float tt = t + t2 + t4 + t8 + t16;
          if (diag) { // exact diagonal: K_ii = 5 (kills fp8 quantization bias)
            int grow = wi * 64 + ti * 32 + q5 * 4 + g * 8 + rr;
            int gcol = wj * 64 + tj * 32 + c5;
            if (grow == gcol) tt = 5.f;
          }
          lsum += tt;
        }
      }
    }
  }
#pragma unroll
  for (int off = 32; off > 0; off >>= 1) lsum += __shfl_down(lsum, off);
  if (lane == 0) red[w] = lsum;
  __syncthreads();
  if (tid == 0)
    atomicAdd(accbuf + (blockIdx.x & 31) * 16,
              wgt * (red[0] + red[1] + red[2] + red[3]));
}

// ---------------- K3: finalize ----------------------------------------------
__global__ void k_fin(const float* __restrict__ accbuf, float* __restrict__ out) {
  int lane = threadIdx.x & 63;
  float s = (lane < 32) ? accbuf[lane * 16] : 0.f;
#pragma unroll
  for (int off = 32; off > 0; off >>= 1) s += __shfl_down(s, off);
  if (threadIdx.x == 0) out[0] = s / 16777216.f; // / 4096^2
}

extern "C" void kernel_launch(void* const* d_in, const int* in_sizes, int n_in,
                              void* d_out, int out_size, void* d_ws, size_t ws_size,
                              hipStream_t stream) {
  const float* src = (const float*)d_in[0];
  const float* tgt = (const float*)d_in[1];
  char* ws = (char*)d_ws;
  u8* Xq = (u8*)ws;                                  // 2 MiB swizzled fp8
  size_t off = (size_t)NROW * DIM;
  float* sq = (float*)(ws + off);   off += NROW * 4; // 32 KiB row |x|^2
  float* gbuf = (float*)(ws + off);                  // colsum/ss/acc slots
  float* out = (float*)d_out;

  hipMemsetAsync(gbuf, 0, G_ZBYTES, stream);
  k_prep<<<PBLK, 256, 0, stream>>>(src, tgt, Xq, sq, gbuf);
  k_main<<<NBLK, 256, 0, stream>>>(Xq, sq, gbuf, gbuf + G_ACC);
  k_fin<<<1, 64, 0, stream>>>(gbuf + G_ACC, out);
}